// Round 1
// 607.715 us; speedup vs baseline: 1.0375x; 1.0375x over previous
//
#include <hip/hip_runtime.h>
#include <hip/hip_bf16.h>
#include <stdint.h>
#include <stddef.h>

// Problem constants (from reference)
#define D_ENC 512
#define D_J   640
#define VOCAB 1024
#define BB    8
#define TT    200
#define UU    50
// M rows of the joint GEMM = B*T*U = 80000 = 1250 * 64 exactly

typedef __bf16 bf16x8 __attribute__((ext_vector_type(8)));
typedef float  f32x4  __attribute__((ext_vector_type(4)));

// RNE float -> bf16 (bit-level; valid for finite inputs, which ours are)
static __device__ __forceinline__ unsigned f2bf(float x) {
    union { float f; unsigned u; } v; v.f = x;
    unsigned r = v.u + 0x7FFFu + ((v.u >> 16) & 1u);
    return r >> 16;
}
static __device__ __forceinline__ unsigned pk2(float a, float b) {
    return f2bf(a) | (f2bf(b) << 16);
}

static __device__ __forceinline__ float tanh_fast(float x) {
    float ax = __builtin_fabsf(x);
    float e  = __expf(-2.0f * ax);                       // in (0,1], underflows to 0 for big |x|
    float t  = (1.0f - e) * __builtin_amdgcn_rcpf(1.0f + e);
    return __builtin_copysignf(t, x);
}

// ---------------- kernel 1: W_out fp32 -> bf16 ----------------
__global__ void wcvt_kernel(const float* __restrict__ src,
                            unsigned short* __restrict__ dst, int n8) {
    int i = blockIdx.x * blockDim.x + threadIdx.x;
    if (i >= n8) return;
    const float4* s = (const float4*)src + (size_t)i * 2;
    float4 a = s[0], b = s[1];
    uint4 o;
    o.x = pk2(a.x, a.y); o.y = pk2(a.z, a.w);
    o.z = pk2(b.x, b.y); o.w = pk2(b.z, b.w);
    ((uint4*)dst)[i] = o;
}

// ---------------- kernel 2/3: projection GEMM ----------------
// C[M][640] = A[M][K] * W[640][K]^T + bias.  Tile 64x64, BK=64, 4 waves.
// Wave w computes rows [w*16, w*16+16) x all 64 n.
__global__ void proj_gemm(const float* __restrict__ A, const float* __restrict__ W,
                          const float* __restrict__ bias, float* __restrict__ C,
                          int M, int K) {
    __shared__ __align__(16) unsigned short Alds[64 * 72];
    __shared__ __align__(16) unsigned short Blds[64 * 72];
    const int tid  = threadIdx.x;
    const int lane = tid & 63, w = tid >> 6;
    const int l15  = lane & 15, quad = lane >> 4;
    const int m0 = blockIdx.x * 64, n0 = blockIdx.y * 64;
    const int srow = tid >> 2, sq = tid & 3;     // staging: 4 threads/row, 16 elems each

    f32x4 acc[4];
#pragma unroll
    for (int i = 0; i < 4; ++i) acc[i] = (f32x4){0.f, 0.f, 0.f, 0.f};

    const int am = m0 + srow;
    const float* arow = A + (size_t)am * K + sq * 16;
    const float* wrow = W + (size_t)(n0 + srow) * K + sq * 16;
    unsigned short* adst = &Alds[srow * 72 + sq * 16];
    unsigned short* bdst = &Blds[srow * 72 + sq * 16];

    for (int k0 = 0; k0 < K; k0 += 64) {
        uint4 wa0, wa1;
        if (am < M) {
            const float4* p = (const float4*)(arow + k0);
            float4 x0 = p[0], x1 = p[1], x2 = p[2], x3 = p[3];
            wa0.x = pk2(x0.x, x0.y); wa0.y = pk2(x0.z, x0.w);
            wa0.z = pk2(x1.x, x1.y); wa0.w = pk2(x1.z, x1.w);
            wa1.x = pk2(x2.x, x2.y); wa1.y = pk2(x2.z, x2.w);
            wa1.z = pk2(x3.x, x3.y); wa1.w = pk2(x3.z, x3.w);
        } else {
            wa0 = make_uint4(0u, 0u, 0u, 0u); wa1 = wa0;
        }
        uint4 wb0, wb1;
        {
            const float4* p = (const float4*)(wrow + k0);
            float4 x0 = p[0], x1 = p[1], x2 = p[2], x3 = p[3];
            wb0.x = pk2(x0.x, x0.y); wb0.y = pk2(x0.z, x0.w);
            wb0.z = pk2(x1.x, x1.y); wb0.w = pk2(x1.z, x1.w);
            wb1.x = pk2(x2.x, x2.y); wb1.y = pk2(x2.z, x2.w);
            wb1.z = pk2(x3.x, x3.y); wb1.w = pk2(x3.z, x3.w);
        }
        *(uint4*)adst = wa0; *(uint4*)(adst + 8) = wa1;
        *(uint4*)bdst = wb0; *(uint4*)(bdst + 8) = wb1;
        __syncthreads();
#pragma unroll
        for (int ks = 0; ks < 2; ++ks) {
            bf16x8 af = *(const bf16x8*)&Alds[(w * 16 + l15) * 72 + ks * 32 + quad * 8];
#pragma unroll
            for (int nt = 0; nt < 4; ++nt) {
                bf16x8 bf = *(const bf16x8*)&Blds[(nt * 16 + l15) * 72 + ks * 32 + quad * 8];
                acc[nt] = __builtin_amdgcn_mfma_f32_16x16x32_bf16(af, bf, acc[nt], 0, 0, 0);
            }
        }
        __syncthreads();
    }
#pragma unroll
    for (int nt = 0; nt < 4; ++nt) {
        const int n = n0 + nt * 16 + l15;
        const float bo = bias[n];
#pragma unroll
        for (int r = 0; r < 4; ++r) {
            const int mm = m0 + w * 16 + quad * 4 + r;
            if (mm < M) C[(size_t)mm * D_J + n] = acc[nt][r] + bo;
        }
    }
}

// ---------------- kernel 4: fused joint GEMM ----------------
// out[m][v] = sum_j W_out[v][j] * tanh(encp[bt][j] + predp[b*U+u][j]) + b_out[v]
// m = (b*T+t)*U+u.
// Tile 64(M) x 1024(N), 8 waves, each wave owns a 128-wide N slice (acc[4][8]).
// tanh A-tile computed EXACTLY ONCE per (m,k) (was 4x redundant), staged through
// double-buffered LDS -> ONE barrier per K-step; next tile's tanh VALU overlaps
// this tile's MFMAs. B frags loaded direct from global (L2-hot bf16 W_out).
#define TANH4(d, e, p)                         \
    d.x = tanh_fast(e.x + p.x);                \
    d.y = tanh_fast(e.y + p.y);                \
    d.z = tanh_fast(e.z + p.z);                \
    d.w = tanh_fast(e.w + p.w);

// stage 8 elems: tanh(enc+pred) -> bf16 -> LDS (one uint4 write)
#define STAGE(dstp, kk)                                      \
    {                                                        \
        const float4* ep = (const float4*)(erow + (kk));     \
        const float4* pp = (const float4*)(prow + (kk));     \
        float4 e0 = ep[0], e1 = ep[1];                       \
        float4 p0 = pp[0], p1 = pp[1];                       \
        float4 t0, t1;                                       \
        TANH4(t0, e0, p0); TANH4(t1, e1, p1);                \
        uint4 s;                                             \
        s.x = pk2(t0.x, t0.y); s.y = pk2(t0.z, t0.w);        \
        s.z = pk2(t1.x, t1.y); s.w = pk2(t1.z, t1.w);        \
        *(uint4*)(dstp) = s;                                 \
    }

__global__ void __launch_bounds__(512, 2)
joint_kernel(const float* __restrict__ encp,   // [1600][640]
             const float* __restrict__ predp,  // [400][640]
             const unsigned short* __restrict__ Wb, // bf16 [1024][640]
             const float* __restrict__ bout,   // [1024]
             float* __restrict__ out) {        // [80000][1024]
    // double-buffered A tile, pad 64->72 shorts/row
    __shared__ __align__(16) unsigned short Alds[2][64 * 72];
    const int tid  = threadIdx.x;
    const int lane = tid & 63, w = tid >> 6;        // 8 waves
    const int l15  = lane & 15, quad = (lane >> 4) & 3;
    const int m0 = blockIdx.x * 64;
    const int n0 = w * 128;                          // each wave: 128-wide N slice
    const int srow = tid >> 3, sq = tid & 7;         // staging: 8 threads/row, 8 elems each

    // row decode for the staging row this thread feeds (always valid: 64 | 80000)
    const int m  = m0 + srow;
    const int bt = m / UU;
    const int u  = m - bt * UU;
    const int b  = bt / TT;
    const float* erow = encp  + (size_t)bt * D_J + sq * 8;
    const float* prow = predp + (size_t)(b * UU + u) * D_J + sq * 8;
    const unsigned short* wrow = Wb + (size_t)(n0 + l15) * D_J + quad * 8;
    unsigned short* adst0 = &Alds[0][srow * 72 + sq * 8];
    unsigned short* adst1 = adst0 + 64 * 72;

    f32x4 acc[4][8];
#pragma unroll
    for (int i = 0; i < 4; ++i)
#pragma unroll
        for (int j = 0; j < 8; ++j) acc[i][j] = (f32x4){0.f, 0.f, 0.f, 0.f};

    // prologue: stage K-tile 0 into buffer 0
    STAGE(adst0, 0);
    __syncthreads();

    for (int kt = 0; kt < 10; ++kt) {
        const int k0  = kt * 64;
        const int cur = kt & 1;
        // stage next K-tile into the other buffer: global loads issue first,
        // tanh VALU overlaps the MFMA cluster below (separate pipes)
        if (kt < 9) STAGE(cur ? adst0 : adst1, k0 + 64);

#pragma unroll
        for (int ks = 0; ks < 2; ++ks) {
            uint4 bfr[8];
#pragma unroll
            for (int nt = 0; nt < 8; ++nt)
                bfr[nt] = *(const uint4*)(wrow + (size_t)nt * 16 * D_J + k0 + ks * 32);
            bf16x8 af[4];
#pragma unroll
            for (int mt = 0; mt < 4; ++mt)
                af[mt] = *(const bf16x8*)&Alds[cur][(mt * 16 + l15) * 72 + ks * 32 + quad * 8];
#pragma unroll
            for (int mt = 0; mt < 4; ++mt)
#pragma unroll
                for (int nt = 0; nt < 8; ++nt)
                    acc[mt][nt] = __builtin_amdgcn_mfma_f32_16x16x32_bf16(
                        af[mt], __builtin_bit_cast(bf16x8, bfr[nt]), acc[mt][nt], 0, 0, 0);
        }
        __syncthreads();   // single barrier per K-step (double-buffered)
    }

    // epilogue: C/D layout col(n)=lane&15, row(m)=quad*4+reg
#pragma unroll
    for (int nt = 0; nt < 8; ++nt) {
        const int n = n0 + nt * 16 + l15;
        const float bo = bout[n];
#pragma unroll
        for (int mt = 0; mt < 4; ++mt) {
#pragma unroll
            for (int r = 0; r < 4; ++r) {
                const int mm = m0 + mt * 16 + quad * 4 + r;
                out[(size_t)mm * VOCAB + n] = acc[mt][nt][r] + bo;
            }
        }
    }
}

extern "C" void kernel_launch(void* const* d_in, const int* in_sizes, int n_in,
                              void* d_out, int out_size, void* d_ws, size_t ws_size,
                              hipStream_t stream) {
    const float* enc    = (const float*)d_in[0];   // (8,200,512)
    const float* pred   = (const float*)d_in[1];   // (8,50,640)
    const float* W_enc  = (const float*)d_in[2];   // (640,512)
    const float* b_enc  = (const float*)d_in[3];   // (640)
    const float* W_pred = (const float*)d_in[4];   // (640,640)
    const float* b_pred = (const float*)d_in[5];   // (640)
    const float* W_out  = (const float*)d_in[6];   // (1024,640)
    const float* b_out  = (const float*)d_in[7];   // (1024)
    float* out = (float*)d_out;                    // (8,200,50,1024)

    // workspace layout (needs ~6.43 MB)
    char* ws = (char*)d_ws;
    unsigned short* Wob = (unsigned short*)ws;                       // 1,310,720 B
    float* encp  = (float*)(ws + 1310720);                           // 4,096,000 B
    float* predp = (float*)(ws + 1310720 + 4096000);                 // 1,024,000 B

    wcvt_kernel<<<320, 256, 0, stream>>>(W_out, Wob, 81920);          // 1024*640/8
    proj_gemm<<<dim3(25, 10), 256, 0, stream>>>(enc,  W_enc,  b_enc,  encp,  1600, 512);
    proj_gemm<<<dim3(7, 10),  256, 0, stream>>>(pred, W_pred, b_pred, predp, 400,  640);
    joint_kernel<<<dim3(1250), 512, 0, stream>>>(encp, predp, Wob, b_out, out);
}